// Round 1
// baseline (856.867 us; speedup 1.0000x reference)
//
#include <hip/hip_runtime.h>
#include <cstdio>
#include <cstdint>

// Bahdanau attention, N=64, L=1024, H=1024.
//   d = dec_h @ W_dec + b_dec                         (64x1024, small)
//   e = enc @ W_enc                                    (65536x1024x1024 GEMM, bf16 MFMA, fused)
//   scores[m] = sum_col tanh(e + d[n,col]+b_enc[col]) * W_one[col]   (fused epilogue)
//   alpha = softmax(scores)  (b_one drops: softmax shift-invariant)
//   ctx = alpha @ enc  (bf16 copy), h_att = ctx @ W_att + b_att

typedef __bf16 bf16x8 __attribute__((ext_vector_type(8)));
typedef float f32x4 __attribute__((ext_vector_type(4)));

#define M_TOT 65536  // 64 * 1024 rows

static __device__ __forceinline__ unsigned short f2b(float f) {
  union { float f; unsigned u; } v; v.f = f;
  unsigned r = (v.u + 0x7fffu + ((v.u >> 16) & 1u)) >> 16;  // RNE
  return (unsigned short)r;
}
static __device__ __forceinline__ float b2f(unsigned short u) {
  union { unsigned u; float f; } v; v.u = ((unsigned)u) << 16;
  return v.f;
}
static __device__ __forceinline__ void gl_lds16(const void* g, void* l) {
  __builtin_amdgcn_global_load_lds(
      (const __attribute__((address_space(1))) unsigned int*)g,
      (__attribute__((address_space(3))) unsigned int*)l, 16, 0, 0);
}

// ---- enc f32 -> bf16 ----
__global__ void conv_enc(const float4* __restrict__ in, ushort4* __restrict__ out, int n4) {
  int idx = blockIdx.x * blockDim.x + threadIdx.x;
  int stride = gridDim.x * blockDim.x;
  for (; idx < n4; idx += stride) {
    float4 v = in[idx];
    ushort4 o;
    o.x = f2b(v.x); o.y = f2b(v.y); o.z = f2b(v.z); o.w = f2b(v.w);
    out[idx] = o;
  }
}

// ---- W_enc (K x N f32) -> Bt (N x K bf16) ----
__global__ void transpose_conv(const float* __restrict__ W, unsigned short* __restrict__ Bt) {
  __shared__ float t[32][33];
  int bx = blockIdx.x * 32;  // k base
  int by = blockIdx.y * 32;  // n base
  int tx = threadIdx.x, ty = threadIdx.y;  // 32 x 8
  for (int i = 0; i < 32; i += 8)
    t[ty + i][tx] = W[(size_t)(bx + ty + i) * 1024 + by + tx];
  __syncthreads();
  for (int i = 0; i < 32; i += 8)
    Bt[(size_t)(by + ty + i) * 1024 + bx + tx] = f2b(t[tx][ty + i]);
}

// ---- addterm[n][j] = sum_k dec_h[n][k] W_dec[k][j] + b_dec[j] + b_enc[j] ----
__global__ void dterm_k(const float* __restrict__ dec_h, const float* __restrict__ W_dec,
                        const float* __restrict__ b_dec, const float* __restrict__ b_enc,
                        float* __restrict__ addterm) {
  __shared__ float xs[1024];
  int n = blockIdx.y;
  int j = blockIdx.x * 256 + threadIdx.x;
  for (int i = threadIdx.x; i < 1024; i += 256) xs[i] = dec_h[n * 1024 + i];
  __syncthreads();
  float s = 0.f;
  #pragma unroll 8
  for (int k = 0; k < 1024; ++k) s += xs[k] * W_dec[(size_t)k * 1024 + j];
  addterm[n * 1024 + j] = s + b_dec[j] + b_enc[j];
}

// ---- fused e-GEMM + tanh + dot(W_one): spart[row][16] partial scores ----
// A: [M_TOT][1024] bf16 row-major. Bt: [1024 n][1024 k] bf16.
// 128x128 tile, BK=32, 4 waves 2x2, each wave 64x64 via 4x4 of 16x16x32 MFMA.
// LDS chunk-transposed layout: 16B chunk (m,c) at position c*128+m -> conflict-free ds_read_b128.
__global__ __launch_bounds__(256) void score_gemm(
    const unsigned short* __restrict__ A, const unsigned short* __restrict__ Bt,
    const float* __restrict__ addterm, const float* __restrict__ Wone,
    float* __restrict__ spart) {
  __shared__ __align__(16) unsigned short lA[4096];  // 8 KB
  __shared__ __align__(16) unsigned short lB[4096];
  const int tid = threadIdx.x;
  const int lane = tid & 63, wave = tid >> 6;
  const int wm = wave >> 1, wn = wave & 1;
  const int q = lane >> 4, r = lane & 15;
  const int nb = blockIdx.x, mb = blockIdx.y;
  const size_t tileM = (size_t)mb * 128;
  const int tileN = nb * 128;

  f32x4 acc[4][4];
  #pragma unroll
  for (int i = 0; i < 4; ++i)
    #pragma unroll
    for (int j = 0; j < 4; ++j) acc[i][j] = (f32x4){0.f, 0.f, 0.f, 0.f};

  // wave w stages k-chunk c=w for rows i*64+lane (i=0,1); deposits land at
  // LDS position p = w*128 + i*64 + lane  (p = c*128 + m)
  const unsigned short* gA0 = A + (tileM + lane) * 1024 + wave * 8;
  const unsigned short* gA1 = gA0 + (size_t)64 * 1024;
  const unsigned short* gB0 = Bt + (size_t)(tileN + lane) * 1024 + wave * 8;
  const unsigned short* gB1 = gB0 + (size_t)64 * 1024;
  unsigned short* dA0 = &lA[wave * 1024];
  unsigned short* dA1 = &lA[wave * 1024 + 512];
  unsigned short* dB0 = &lB[wave * 1024];
  unsigned short* dB1 = &lB[wave * 1024 + 512];

  for (int kt = 0; kt < 32; ++kt) {
    __syncthreads();
    const int ko = kt * 32;
    gl_lds16(gA0 + ko, dA0);
    gl_lds16(gA1 + ko, dA1);
    gl_lds16(gB0 + ko, dB0);
    gl_lds16(gB1 + ko, dB1);
    __syncthreads();
    bf16x8 af[4], bg[4];
    #pragma unroll
    for (int mi = 0; mi < 4; ++mi)
      af[mi] = *(const bf16x8*)&lA[(q * 128 + wm * 64 + mi * 16 + r) * 8];
    #pragma unroll
    for (int ni = 0; ni < 4; ++ni)
      bg[ni] = *(const bf16x8*)&lB[(q * 128 + wn * 64 + ni * 16 + r) * 8];
    #pragma unroll
    for (int mi = 0; mi < 4; ++mi)
      #pragma unroll
      for (int ni = 0; ni < 4; ++ni)
        acc[mi][ni] = __builtin_amdgcn_mfma_f32_16x16x32_bf16(af[mi], bg[ni], acc[mi][ni], 0, 0, 0);
  }

  // epilogue: D element (row = mi*16 + q*4 + rr, col = ni*16 + r) within wave tile
  const int nrow = (int)(tileM >> 10);
  float addv[4], wv[4];
  #pragma unroll
  for (int ni = 0; ni < 4; ++ni) {
    int col = tileN + wn * 64 + ni * 16 + r;
    addv[ni] = addterm[nrow * 1024 + col];
    wv[ni] = Wone[col];
  }
  #pragma unroll
  for (int mi = 0; mi < 4; ++mi) {
    #pragma unroll
    for (int rr = 0; rr < 4; ++rr) {
      float s = 0.f;
      #pragma unroll
      for (int ni = 0; ni < 4; ++ni)
        s += tanhf(acc[mi][ni][rr] + addv[ni]) * wv[ni];
      s += __shfl_xor(s, 1);
      s += __shfl_xor(s, 2);
      s += __shfl_xor(s, 4);
      s += __shfl_xor(s, 8);
      if (r == 0) {
        size_t row = tileM + wm * 64 + mi * 16 + q * 4 + rr;
        spart[row * 16 + nb * 2 + wn] = s;
      }
    }
  }
}

// ---- softmax over L=1024 per n; alpha -> d_out[65536..] ----
__global__ void softmax_k(const float* __restrict__ spart, float* __restrict__ alpha) {
  int n = blockIdx.x, t = threadIdx.x;
  __shared__ float red[8];
  float sv[4];
  #pragma unroll
  for (int i = 0; i < 4; ++i) {
    int l = i * 256 + t;
    const float4* p = (const float4*)(spart + ((size_t)n * 1024 + l) * 16);
    float4 v0 = p[0], v1 = p[1], v2 = p[2], v3 = p[3];
    sv[i] = (v0.x + v0.y + v0.z + v0.w) + (v1.x + v1.y + v1.z + v1.w) +
            (v2.x + v2.y + v2.z + v2.w) + (v3.x + v3.y + v3.z + v3.w);
  }
  float m = fmaxf(fmaxf(sv[0], sv[1]), fmaxf(sv[2], sv[3]));
  for (int o = 32; o > 0; o >>= 1) m = fmaxf(m, __shfl_xor(m, o));
  if ((t & 63) == 0) red[t >> 6] = m;
  __syncthreads();
  float gm = fmaxf(fmaxf(red[0], red[1]), fmaxf(red[2], red[3]));
  float e[4], s = 0.f;
  #pragma unroll
  for (int i = 0; i < 4; ++i) { e[i] = expf(sv[i] - gm); s += e[i]; }
  for (int o = 32; o > 0; o >>= 1) s += __shfl_xor(s, o);
  if ((t & 63) == 0) red[4 + (t >> 6)] = s;
  __syncthreads();
  float inv = 1.0f / (red[4] + red[5] + red[6] + red[7]);
  #pragma unroll
  for (int i = 0; i < 4; ++i) alpha[(size_t)n * 1024 + i * 256 + t] = e[i] * inv;
}

// ---- ctx partials: ctxp[lc][n][1024] = sum over 64 l of alpha * enc_bf16 ----
__global__ void ctx_k(const unsigned short* __restrict__ Abf, const float* __restrict__ alpha,
                      float* __restrict__ ctxp) {
  int n = blockIdx.y, lc = blockIdx.x, t = threadIdx.x;
  __shared__ float al[64];
  if (t < 64) al[t] = alpha[n * 1024 + lc * 64 + t];
  __syncthreads();
  float a0 = 0.f, a1 = 0.f, a2 = 0.f, a3 = 0.f;
  const unsigned short* base = Abf + ((size_t)n * 1024 + lc * 64) * 1024 + t * 4;
  #pragma unroll 4
  for (int l = 0; l < 64; ++l) {
    ushort4 v = *(const ushort4*)(base + (size_t)l * 1024);
    float w = al[l];
    a0 += w * b2f(v.x); a1 += w * b2f(v.y); a2 += w * b2f(v.z); a3 += w * b2f(v.w);
  }
  float* o = ctxp + ((size_t)lc * 64 + n) * 1024 + t * 4;
  o[0] = a0; o[1] = a1; o[2] = a2; o[3] = a3;
}

// ---- h_att[n][j] = sum_k ctx[n][k] W_att[k][j] + b_att[j] -> d_out[0..65535] ----
__global__ void hatt_k(const float* __restrict__ ctxp, const float* __restrict__ W_att,
                       const float* __restrict__ b_att, float* __restrict__ out) {
  __shared__ float cs[1024];
  int n = blockIdx.y;
  int j = blockIdx.x * 256 + threadIdx.x;
  for (int i = threadIdx.x; i < 1024; i += 256) {
    float s = 0.f;
    #pragma unroll
    for (int p = 0; p < 16; ++p) s += ctxp[((size_t)p * 64 + n) * 1024 + i];
    cs[i] = s;
  }
  __syncthreads();
  float s = 0.f;
  #pragma unroll 8
  for (int k = 0; k < 1024; ++k) s += cs[k] * W_att[(size_t)k * 1024 + j];
  out[n * 1024 + j] = s + b_att[j];
}

extern "C" void kernel_launch(void* const* d_in, const int* in_sizes, int n_in,
                              void* d_out, int out_size, void* d_ws, size_t ws_size,
                              hipStream_t stream) {
  const float* dec_h = (const float*)d_in[0];
  const float* enc   = (const float*)d_in[1];
  const float* W_dec = (const float*)d_in[2];
  const float* b_dec = (const float*)d_in[3];
  const float* W_enc = (const float*)d_in[4];
  const float* b_enc = (const float*)d_in[5];
  const float* W_one = (const float*)d_in[6];
  // d_in[7] = b_one: softmax is shift-invariant, alpha/h_att unaffected -> unused
  const float* W_att = (const float*)d_in[8];
  const float* b_att = (const float*)d_in[9];
  float* out = (float*)d_out;

  char* ws = (char*)d_ws;
  const size_t OFF_A    = 0;                       // 65536*1024*2 = 134217728
  const size_t OFF_BT   = 134217728;               // 1024*1024*2  = 2097152
  const size_t OFF_ADD  = OFF_BT + 2097152;        // 64*1024*4    = 262144
  const size_t OFF_SP   = OFF_ADD + 262144;        // 65536*16*4   = 4194304
  const size_t OFF_CTXP = OFF_SP + 4194304;        // 16*64*1024*4 = 4194304
  const size_t NEED     = OFF_CTXP + 4194304;      // ~138.3 MiB
  if (ws_size < NEED) {
    fprintf(stderr, "kernel_launch: ws too small (%zu < %zu)\n", ws_size, NEED);
    return;
  }
  unsigned short* Abf = (unsigned short*)(ws + OFF_A);
  unsigned short* Bt  = (unsigned short*)(ws + OFF_BT);
  float* addterm = (float*)(ws + OFF_ADD);
  float* spart   = (float*)(ws + OFF_SP);
  float* ctxp    = (float*)(ws + OFF_CTXP);
  float* alpha   = out + 65536;

  conv_enc<<<4096, 256, 0, stream>>>((const float4*)enc, (ushort4*)Abf, 16777216);
  transpose_conv<<<dim3(32, 32), dim3(32, 8), 0, stream>>>(W_enc, Bt);
  dterm_k<<<dim3(4, 64), 256, 0, stream>>>(dec_h, W_dec, b_dec, b_enc, addterm);
  score_gemm<<<dim3(8, 512), 256, 0, stream>>>(Abf, Bt, addterm, W_one, spart);
  softmax_k<<<64, 256, 0, stream>>>(spart, alpha);
  ctx_k<<<dim3(16, 64), 256, 0, stream>>>(Abf, alpha, ctxp);
  hatt_k<<<dim3(4, 64), 256, 0, stream>>>(ctxp, W_att, b_att, out);
}

// Round 2
// 834.886 us; speedup vs baseline: 1.0263x; 1.0263x over previous
//
#include <hip/hip_runtime.h>
#include <cstdio>
#include <cstdint>

// Bahdanau attention, N=64, L=1024, H=1024.
//   d = dec_h @ W_dec + b_dec                         (64x1024, small)
//   e = enc @ W_enc                                    (65536x1024x1024 GEMM, bf16 MFMA, fused)
//   scores[m] = sum_col tanh(e + d[n,col]+b_enc[col]) * W_one[col]   (fused epilogue)
//   alpha = softmax(scores)  (b_one drops: softmax shift-invariant)
//   ctx = alpha @ enc  (bf16 copy), h_att = ctx @ W_att + b_att

typedef __bf16 bf16x8 __attribute__((ext_vector_type(8)));
typedef float f32x4 __attribute__((ext_vector_type(4)));
typedef unsigned short us8 __attribute__((ext_vector_type(8)));

static __device__ __forceinline__ unsigned short f2b(float f) {
  union { float f; unsigned u; } v; v.f = f;
  unsigned r = (v.u + 0x7fffu + ((v.u >> 16) & 1u)) >> 16;  // RNE
  return (unsigned short)r;
}
static __device__ __forceinline__ float b2f(unsigned short u) {
  union { unsigned u; float f; } v; v.u = ((unsigned)u) << 16;
  return v.f;
}
static __device__ __forceinline__ void gl_lds16(const void* g, void* l) {
  __builtin_amdgcn_global_load_lds(
      (const __attribute__((address_space(1))) unsigned int*)g,
      (__attribute__((address_space(3))) unsigned int*)l, 16, 0, 0);
}

// ---- enc f32 -> bf16 ----
__global__ void conv_enc(const float4* __restrict__ in, ushort4* __restrict__ out, int n4) {
  int idx = blockIdx.x * blockDim.x + threadIdx.x;
  int stride = gridDim.x * blockDim.x;
  for (; idx < n4; idx += stride) {
    float4 v = in[idx];
    ushort4 o;
    o.x = f2b(v.x); o.y = f2b(v.y); o.z = f2b(v.z); o.w = f2b(v.w);
    out[idx] = o;
  }
}

// ---- W_enc (K x N f32) -> Bt (N x K bf16) ----
__global__ void transpose_conv(const float* __restrict__ W, unsigned short* __restrict__ Bt) {
  __shared__ float t[32][33];
  int bx = blockIdx.x * 32;  // k base
  int by = blockIdx.y * 32;  // n base
  int tx = threadIdx.x, ty = threadIdx.y;  // 32 x 8
  for (int i = 0; i < 32; i += 8)
    t[ty + i][tx] = W[(size_t)(bx + ty + i) * 1024 + by + tx];
  __syncthreads();
  for (int i = 0; i < 32; i += 8)
    Bt[(size_t)(by + ty + i) * 1024 + bx + tx] = f2b(t[tx][ty + i]);
}

// ---- addterm[n][j] = sum_k dec_h[n][k] W_dec[k][j] + b_dec[j] + b_enc[j] ----
__global__ void dterm_k(const float* __restrict__ dec_h, const float* __restrict__ W_dec,
                        const float* __restrict__ b_dec, const float* __restrict__ b_enc,
                        float* __restrict__ addterm) {
  __shared__ float xs[1024];
  int n = blockIdx.y;
  int j = blockIdx.x * 256 + threadIdx.x;
  for (int i = threadIdx.x; i < 1024; i += 256) xs[i] = dec_h[n * 1024 + i];
  __syncthreads();
  float s = 0.f;
  #pragma unroll 8
  for (int k = 0; k < 1024; ++k) s += xs[k] * W_dec[(size_t)k * 1024 + j];
  addterm[n * 1024 + j] = s + b_dec[j] + b_enc[j];
}

// ---- fused e-GEMM + tanh + dot(W_one): spart[row][16] partial scores ----
// A: [65536][1024] bf16 row-major. Bt: [1024 n][1024 k] bf16.
// 128x128 tile, BK=64, 4 waves 2x2, each wave 64x64 via 4x4 of 16x16x32 MFMA.
// LDS chunk-transposed layout: 16B chunk (m,c) at (c*128+m)*8 shorts -> conflict-free ds_read_b128.
// XCD swizzle: hw places flat%8 on xcd flat%8; we give the 8 nb-siblings of one
// A-tile flat ids {super*64 + nb*8 + r} (same residue r, 64-id window) -> same XCD L2.
__global__ __launch_bounds__(256) void score_gemm(
    const unsigned short* __restrict__ A, const unsigned short* __restrict__ Bt,
    const float* __restrict__ addterm, const float* __restrict__ Wone,
    float* __restrict__ spart) {
  __shared__ __align__(16) unsigned short lA[8192];  // 16 KB
  __shared__ __align__(16) unsigned short lB[8192];
  const int tid = threadIdx.x;
  const int lane = tid & 63, wave = tid >> 6;
  const int wm = wave >> 1, wn = wave & 1;
  const int q = lane >> 4, r = lane & 15;
  const int flat = blockIdx.x;
  const int nb = (flat >> 3) & 7;
  const int mb = ((flat >> 6) << 3) + (flat & 7);
  const size_t tileM = (size_t)mb * 128;
  const int tileN = nb * 128;

  f32x4 acc[4][4];
  #pragma unroll
  for (int i = 0; i < 4; ++i)
    #pragma unroll
    for (int j = 0; j < 4; ++j) acc[i][j] = (f32x4){0.f, 0.f, 0.f, 0.f};

  // wave w stages k-chunks c = 2w, 2w+1 for rows i*64+lane (i=0,1).
  // LDS dest is wave-uniform base + lane*16B: base = (c*128 + i*64)*8 shorts.
  const unsigned short* gA[2][2];
  const unsigned short* gB[2][2];
  unsigned short* dA[2][2];
  unsigned short* dB[2][2];
  #pragma unroll
  for (int cc = 0; cc < 2; ++cc) {
    int c = wave * 2 + cc;
    #pragma unroll
    for (int i = 0; i < 2; ++i) {
      gA[cc][i] = A + (tileM + i * 64 + lane) * 1024 + c * 8;
      gB[cc][i] = Bt + (size_t)(tileN + i * 64 + lane) * 1024 + c * 8;
      dA[cc][i] = &lA[(c * 128 + i * 64) * 8];
      dB[cc][i] = &lB[(c * 128 + i * 64) * 8];
    }
  }

  for (int kt = 0; kt < 16; ++kt) {
    __syncthreads();
    const int ko = kt * 64;
    gl_lds16(gA[0][0] + ko, dA[0][0]);
    gl_lds16(gA[0][1] + ko, dA[0][1]);
    gl_lds16(gA[1][0] + ko, dA[1][0]);
    gl_lds16(gA[1][1] + ko, dA[1][1]);
    gl_lds16(gB[0][0] + ko, dB[0][0]);
    gl_lds16(gB[0][1] + ko, dB[0][1]);
    gl_lds16(gB[1][0] + ko, dB[1][0]);
    gl_lds16(gB[1][1] + ko, dB[1][1]);
    __syncthreads();
    #pragma unroll
    for (int s = 0; s < 2; ++s) {
      bf16x8 af[4], bg[4];
      #pragma unroll
      for (int mi = 0; mi < 4; ++mi)
        af[mi] = *(const bf16x8*)&lA[((s * 4 + q) * 128 + wm * 64 + mi * 16 + r) * 8];
      #pragma unroll
      for (int ni = 0; ni < 4; ++ni)
        bg[ni] = *(const bf16x8*)&lB[((s * 4 + q) * 128 + wn * 64 + ni * 16 + r) * 8];
      #pragma unroll
      for (int mi = 0; mi < 4; ++mi)
        #pragma unroll
        for (int ni = 0; ni < 4; ++ni)
          acc[mi][ni] = __builtin_amdgcn_mfma_f32_16x16x32_bf16(af[mi], bg[ni], acc[mi][ni], 0, 0, 0);
    }
  }

  // epilogue: D element (row = mi*16 + q*4 + rr, col = ni*16 + r) within wave tile
  const int nrow = (int)(tileM >> 10);
  float addv[4], wv[4];
  #pragma unroll
  for (int ni = 0; ni < 4; ++ni) {
    int col = tileN + wn * 64 + ni * 16 + r;
    addv[ni] = addterm[nrow * 1024 + col];
    wv[ni] = Wone[col];
  }
  #pragma unroll
  for (int mi = 0; mi < 4; ++mi) {
    #pragma unroll
    for (int rr = 0; rr < 4; ++rr) {
      float s = 0.f;
      #pragma unroll
      for (int ni = 0; ni < 4; ++ni)
        s += tanhf(acc[mi][ni][rr] + addv[ni]) * wv[ni];
      s += __shfl_xor(s, 1);
      s += __shfl_xor(s, 2);
      s += __shfl_xor(s, 4);
      s += __shfl_xor(s, 8);
      if (r == 0) {
        size_t row = tileM + wm * 64 + mi * 16 + q * 4 + rr;
        spart[row * 16 + nb * 2 + wn] = s;
      }
    }
  }
}

// ---- softmax over L=1024 per n; alpha -> d_out[65536..] ----
__global__ void softmax_k(const float* __restrict__ spart, float* __restrict__ alpha) {
  int n = blockIdx.x, t = threadIdx.x;
  __shared__ float red[8];
  float sv[4];
  #pragma unroll
  for (int i = 0; i < 4; ++i) {
    int l = i * 256 + t;
    const float4* p = (const float4*)(spart + ((size_t)n * 1024 + l) * 16);
    float4 v0 = p[0], v1 = p[1], v2 = p[2], v3 = p[3];
    sv[i] = (v0.x + v0.y + v0.z + v0.w) + (v1.x + v1.y + v1.z + v1.w) +
            (v2.x + v2.y + v2.z + v2.w) + (v3.x + v3.y + v3.z + v3.w);
  }
  float m = fmaxf(fmaxf(sv[0], sv[1]), fmaxf(sv[2], sv[3]));
  for (int o = 32; o > 0; o >>= 1) m = fmaxf(m, __shfl_xor(m, o));
  if ((t & 63) == 0) red[t >> 6] = m;
  __syncthreads();
  float gm = fmaxf(fmaxf(red[0], red[1]), fmaxf(red[2], red[3]));
  float e[4], s = 0.f;
  #pragma unroll
  for (int i = 0; i < 4; ++i) { e[i] = expf(sv[i] - gm); s += e[i]; }
  for (int o = 32; o > 0; o >>= 1) s += __shfl_xor(s, o);
  if ((t & 63) == 0) red[4 + (t >> 6)] = s;
  __syncthreads();
  float inv = 1.0f / (red[4] + red[5] + red[6] + red[7]);
  #pragma unroll
  for (int i = 0; i < 4; ++i) alpha[(size_t)n * 1024 + i * 256 + t] = e[i] * inv;
}

// ---- ctx partials: ctxp[lc][n][1024] = sum over 64 l of alpha * enc_bf16 ----
// 128 threads, 16 B/lane loads (ushort8).
__global__ void ctx_k(const unsigned short* __restrict__ Abf, const float* __restrict__ alpha,
                      float* __restrict__ ctxp) {
  int n = blockIdx.y, lc = blockIdx.x, t = threadIdx.x;
  __shared__ float al[64];
  if (t < 64) al[t] = alpha[n * 1024 + lc * 64 + t];
  __syncthreads();
  float a[8] = {0.f, 0.f, 0.f, 0.f, 0.f, 0.f, 0.f, 0.f};
  const unsigned short* base = Abf + ((size_t)n * 1024 + lc * 64) * 1024 + t * 8;
  #pragma unroll 4
  for (int l = 0; l < 64; ++l) {
    us8 v = *(const us8*)(base + (size_t)l * 1024);
    float w = al[l];
    #pragma unroll
    for (int j = 0; j < 8; ++j) a[j] += w * b2f(v[j]);
  }
  float* o = ctxp + ((size_t)lc * 64 + n) * 1024 + t * 8;
  #pragma unroll
  for (int j = 0; j < 8; ++j) o[j] = a[j];
}

// ---- h_att[n][j] = sum_k ctx[n][k] W_att[k][j] + b_att[j] -> d_out[0..65535] ----
__global__ void hatt_k(const float* __restrict__ ctxp, const float* __restrict__ W_att,
                       const float* __restrict__ b_att, float* __restrict__ out) {
  __shared__ float cs[1024];
  int n = blockIdx.y;
  int j = blockIdx.x * 256 + threadIdx.x;
  for (int i = threadIdx.x; i < 1024; i += 256) {
    float s = 0.f;
    #pragma unroll
    for (int p = 0; p < 16; ++p) s += ctxp[((size_t)p * 64 + n) * 1024 + i];
    cs[i] = s;
  }
  __syncthreads();
  float s = 0.f;
  #pragma unroll 8
  for (int k = 0; k < 1024; ++k) s += cs[k] * W_att[(size_t)k * 1024 + j];
  out[n * 1024 + j] = s + b_att[j];
}

extern "C" void kernel_launch(void* const* d_in, const int* in_sizes, int n_in,
                              void* d_out, int out_size, void* d_ws, size_t ws_size,
                              hipStream_t stream) {
  const float* dec_h = (const float*)d_in[0];
  const float* enc   = (const float*)d_in[1];
  const float* W_dec = (const float*)d_in[2];
  const float* b_dec = (const float*)d_in[3];
  const float* W_enc = (const float*)d_in[4];
  const float* b_enc = (const float*)d_in[5];
  const float* W_one = (const float*)d_in[6];
  // d_in[7] = b_one: softmax is shift-invariant, alpha/h_att unaffected -> unused
  const float* W_att = (const float*)d_in[8];
  const float* b_att = (const float*)d_in[9];
  float* out = (float*)d_out;

  char* ws = (char*)d_ws;
  const size_t OFF_A    = 0;                       // 65536*1024*2 = 134217728
  const size_t OFF_BT   = 134217728;               // 1024*1024*2  = 2097152
  const size_t OFF_ADD  = OFF_BT + 2097152;        // 64*1024*4    = 262144
  const size_t OFF_SP   = OFF_ADD + 262144;        // 65536*16*4   = 4194304
  const size_t OFF_CTXP = OFF_SP + 4194304;        // 16*64*1024*4 = 4194304
  const size_t NEED     = OFF_CTXP + 4194304;      // ~138.3 MiB
  if (ws_size < NEED) {
    fprintf(stderr, "kernel_launch: ws too small (%zu < %zu)\n", ws_size, NEED);
    return;
  }
  unsigned short* Abf = (unsigned short*)(ws + OFF_A);
  unsigned short* Bt  = (unsigned short*)(ws + OFF_BT);
  float* addterm = (float*)(ws + OFF_ADD);
  float* spart   = (float*)(ws + OFF_SP);
  float* ctxp    = (float*)(ws + OFF_CTXP);
  float* alpha   = out + 65536;

  conv_enc<<<4096, 256, 0, stream>>>((const float4*)enc, (ushort4*)Abf, 16777216);
  transpose_conv<<<dim3(32, 32), dim3(32, 8), 0, stream>>>(W_enc, Bt);
  dterm_k<<<dim3(4, 64), 256, 0, stream>>>(dec_h, W_dec, b_dec, b_enc, addterm);
  score_gemm<<<4096, 256, 0, stream>>>(Abf, Bt, addterm, W_one, spart);
  softmax_k<<<64, 256, 0, stream>>>(spart, alpha);
  ctx_k<<<dim3(16, 64), 128, 0, stream>>>(Abf, alpha, ctxp);
  hatt_k<<<dim3(4, 64), 256, 0, stream>>>(ctxp, W_att, b_att, out);
}

// Round 3
// 713.851 us; speedup vs baseline: 1.2003x; 1.1696x over previous
//
#include <hip/hip_runtime.h>
#include <cstdio>
#include <cstdint>

// Bahdanau attention, N=64, L=1024, H=1024.
//   d = dec_h @ W_dec + b_dec
//   e = enc @ W_enc   (65536x1024x1024 bf16 MFMA GEMM, fused epilogue below)
//   scores = tanh(d+e+b_enc) . W_one ; alpha = softmax(scores) (b_one drops)
//   ctx = alpha @ enc ; h_att = ctx @ W_att + b_att
//
// A and B are PRE-PACKED into the GEMM's LDS staging order so every
// global_load_lds reads 1KB contiguous:
//   A_packed chunk index = ((T*16 + kt)*8 + c)*128 + m   (16B chunks)
//     T = row>>7, m = row&127, kt = col>>6, c = (col&63)>>3, j = col&7
//   B_packed identical with n-tiles (Tn = 8).

typedef __bf16 bf16x8 __attribute__((ext_vector_type(8)));
typedef float f32x4 __attribute__((ext_vector_type(4)));
typedef unsigned short us8 __attribute__((ext_vector_type(8)));

static __device__ __forceinline__ unsigned short f2b(float f) {
  union { float f; unsigned u; } v; v.f = f;
  unsigned r = (v.u + 0x7fffu + ((v.u >> 16) & 1u)) >> 16;  // RNE
  return (unsigned short)r;
}
static __device__ __forceinline__ float b2f(unsigned short u) {
  union { unsigned u; float f; } v; v.u = ((unsigned)u) << 16;
  return v.f;
}
static __device__ __forceinline__ void gl_lds16(const void* g, void* l) {
  __builtin_amdgcn_global_load_lds(
      (const __attribute__((address_space(1))) unsigned int*)g,
      (__attribute__((address_space(3))) unsigned int*)l, 16, 0, 0);
}
// branch-free tanh: (u-1)/(u+1), u = 2^(2*log2e*|x|); ~9 VALU, err ~1e-7
static __device__ __forceinline__ float fast_tanh(float x) {
  float ax = __builtin_fminf(__builtin_fabsf(x), 18.0f);
  float u = __builtin_amdgcn_exp2f(ax * 2.88539008177792681f);
  float t = (u - 1.0f) * __builtin_amdgcn_rcpf(u + 1.0f);
  return __builtin_copysignf(t, x);
}

// ---- pack A: enc f32 [65536][1024] -> A_packed bf16 tiled; LDS transpose ----
__global__ __launch_bounds__(256) void pack_a(const float* __restrict__ enc,
                                              unsigned short* __restrict__ Ap) {
  __shared__ __align__(16) unsigned short tile[128 * 72];  // row stride 72 shorts (144B)
  const int bid = blockIdx.x;           // 8192 = T(512) x kt(16)
  const int T = bid >> 4, kt = bid & 15;
  const int t = threadIdx.x;
  #pragma unroll
  for (int it = 0; it < 8; ++it) {
    int idx = it * 256 + t;
    int m = idx >> 4, c4 = idx & 15;    // 128 rows x 16 float4
    const float4 v = *(const float4*)(enc + (size_t)(T * 128 + m) * 1024 + kt * 64 + c4 * 4);
    ushort4 o;
    o.x = f2b(v.x); o.y = f2b(v.y); o.z = f2b(v.z); o.w = f2b(v.w);
    *(ushort4*)&tile[m * 72 + c4 * 4] = o;
  }
  __syncthreads();
  #pragma unroll
  for (int it = 0; it < 4; ++it) {
    int p = it * 256 + t;               // chunk pos = c*128 + m
    int c = p >> 7, m = p & 127;
    us8 v = *(const us8*)&tile[m * 72 + c * 8];
    *(us8*)(Ap + ((size_t)bid * 1024 + p) * 8) = v;
  }
}

// ---- pack B: W_enc f32 [k][n] -> B_packed bf16 tiled (transposed) ----
__global__ __launch_bounds__(256) void pack_b(const float* __restrict__ W,
                                              unsigned short* __restrict__ Bp) {
  __shared__ __align__(16) unsigned short tile[128 * 72];  // [n-row m][k-col]
  const int bid = blockIdx.x;           // 128 = Tn(8) x kt(16)
  const int Tn = bid >> 4, kt = bid & 15;
  const int t = threadIdx.x;
  #pragma unroll
  for (int it = 0; it < 8; ++it) {
    int idx = it * 256 + t;
    int kk = idx >> 5, n4 = idx & 31;   // 64 k-rows x 32 float4
    const float4 v = *(const float4*)(W + (size_t)(kt * 64 + kk) * 1024 + Tn * 128 + n4 * 4);
    tile[(n4 * 4 + 0) * 72 + kk] = f2b(v.x);
    tile[(n4 * 4 + 1) * 72 + kk] = f2b(v.y);
    tile[(n4 * 4 + 2) * 72 + kk] = f2b(v.z);
    tile[(n4 * 4 + 3) * 72 + kk] = f2b(v.w);
  }
  __syncthreads();
  #pragma unroll
  for (int it = 0; it < 4; ++it) {
    int p = it * 256 + t;
    int c = p >> 7, m = p & 127;
    us8 v = *(const us8*)&tile[m * 72 + c * 8];
    *(us8*)(Bp + ((size_t)bid * 1024 + p) * 8) = v;
  }
}

// ---- addterm[n][j] = dec_h[n] . W_dec[:,j] + b_dec[j] + b_enc[j] ----
__global__ void dterm_k(const float* __restrict__ dec_h, const float* __restrict__ W_dec,
                        const float* __restrict__ b_dec, const float* __restrict__ b_enc,
                        float* __restrict__ addterm) {
  __shared__ float xs[1024];
  int n = blockIdx.y;
  int j = blockIdx.x * 256 + threadIdx.x;
  for (int i = threadIdx.x; i < 1024; i += 256) xs[i] = dec_h[n * 1024 + i];
  __syncthreads();
  float s = 0.f;
  #pragma unroll 8
  for (int k = 0; k < 1024; ++k) s += xs[k] * W_dec[(size_t)k * 1024 + j];
  addterm[n * 1024 + j] = s + b_dec[j] + b_enc[j];
}

// ---- fused e-GEMM + tanh + dot(W_one): spart[row][16] partial scores ----
// 128x128 tile, BK=64, 4 waves 2x2, 4x4 of 16x16x32 MFMA each.
// Packed inputs -> every gl_lds16 reads 1KB contiguous global.
// XCD swizzle: 8 nb-siblings of one A-tile -> same flat%8 residue (same XCD).
__global__ __launch_bounds__(256) void score_gemm(
    const unsigned short* __restrict__ Ap, const unsigned short* __restrict__ Bp,
    const float* __restrict__ addterm, const float* __restrict__ Wone,
    float* __restrict__ spart) {
  __shared__ __align__(16) unsigned short lA[8192];  // 16 KB
  __shared__ __align__(16) unsigned short lB[8192];
  const int tid = threadIdx.x;
  const int lane = tid & 63, wave = tid >> 6;
  const int wm = wave >> 1, wn = wave & 1;
  const int q = lane >> 4, r = lane & 15;
  const int flat = blockIdx.x;
  const int nb = (flat >> 3) & 7;
  const int mb = ((flat >> 6) << 3) + (flat & 7);
  const size_t tileM = (size_t)mb * 128;
  const int tileN = nb * 128;

  f32x4 acc[4][4];
  #pragma unroll
  for (int i = 0; i < 4; ++i)
    #pragma unroll
    for (int j = 0; j < 4; ++j) acc[i][j] = (f32x4){0.f, 0.f, 0.f, 0.f};

  // wave w stages chunks c = 2w, 2w+1 at m-halves i=0,1 (1KB contiguous each)
  const unsigned short* gA[2][2];
  const unsigned short* gB[2][2];
  unsigned short* dA[2][2];
  unsigned short* dB[2][2];
  #pragma unroll
  for (int cc = 0; cc < 2; ++cc) {
    int c = wave * 2 + cc;
    #pragma unroll
    for (int i = 0; i < 2; ++i) {
      gA[cc][i] = Ap + ((((size_t)mb * 16) * 8 + c) * 128 + i * 64 + lane) * 8;
      gB[cc][i] = Bp + ((((size_t)nb * 16) * 8 + c) * 128 + i * 64 + lane) * 8;
      dA[cc][i] = &lA[(c * 128 + i * 64) * 8];
      dB[cc][i] = &lB[(c * 128 + i * 64) * 8];
    }
  }

  for (int kt = 0; kt < 16; ++kt) {
    __syncthreads();
    const size_t ko = (size_t)kt * 8192;  // 1024 chunks * 8 shorts per kt step
    gl_lds16(gA[0][0] + ko, dA[0][0]);
    gl_lds16(gA[0][1] + ko, dA[0][1]);
    gl_lds16(gA[1][0] + ko, dA[1][0]);
    gl_lds16(gA[1][1] + ko, dA[1][1]);
    gl_lds16(gB[0][0] + ko, dB[0][0]);
    gl_lds16(gB[0][1] + ko, dB[0][1]);
    gl_lds16(gB[1][0] + ko, dB[1][0]);
    gl_lds16(gB[1][1] + ko, dB[1][1]);
    __syncthreads();
    #pragma unroll
    for (int s = 0; s < 2; ++s) {
      bf16x8 af[4], bg[4];
      #pragma unroll
      for (int mi = 0; mi < 4; ++mi)
        af[mi] = *(const bf16x8*)&lA[((s * 4 + q) * 128 + wm * 64 + mi * 16 + r) * 8];
      #pragma unroll
      for (int ni = 0; ni < 4; ++ni)
        bg[ni] = *(const bf16x8*)&lB[((s * 4 + q) * 128 + wn * 64 + ni * 16 + r) * 8];
      #pragma unroll
      for (int mi = 0; mi < 4; ++mi)
        #pragma unroll
        for (int ni = 0; ni < 4; ++ni)
          acc[mi][ni] = __builtin_amdgcn_mfma_f32_16x16x32_bf16(af[mi], bg[ni], acc[mi][ni], 0, 0, 0);
    }
  }

  // epilogue: D element (row = mi*16 + q*4 + rr, col = ni*16 + r) in wave tile
  const int nrow = (int)(tileM >> 10);
  float addv[4], wv[4];
  #pragma unroll
  for (int ni = 0; ni < 4; ++ni) {
    int col = tileN + wn * 64 + ni * 16 + r;
    addv[ni] = addterm[nrow * 1024 + col];
    wv[ni] = Wone[col];
  }
  #pragma unroll
  for (int mi = 0; mi < 4; ++mi) {
    #pragma unroll
    for (int rr = 0; rr < 4; ++rr) {
      float s = 0.f;
      #pragma unroll
      for (int ni = 0; ni < 4; ++ni)
        s += fast_tanh(acc[mi][ni][rr] + addv[ni]) * wv[ni];
      s += __shfl_xor(s, 1);
      s += __shfl_xor(s, 2);
      s += __shfl_xor(s, 4);
      s += __shfl_xor(s, 8);
      if (r == 0) {
        size_t row = tileM + wm * 64 + mi * 16 + q * 4 + rr;
        spart[row * 16 + nb * 2 + wn] = s;
      }
    }
  }
}

// ---- softmax over L=1024 per n; alpha -> d_out[65536..] ----
__global__ void softmax_k(const float* __restrict__ spart, float* __restrict__ alpha) {
  int n = blockIdx.x, t = threadIdx.x;
  __shared__ float red[8];
  float sv[4];
  #pragma unroll
  for (int i = 0; i < 4; ++i) {
    int l = i * 256 + t;
    const float4* p = (const float4*)(spart + ((size_t)n * 1024 + l) * 16);
    float4 v0 = p[0], v1 = p[1], v2 = p[2], v3 = p[3];
    sv[i] = (v0.x + v0.y + v0.z + v0.w) + (v1.x + v1.y + v1.z + v1.w) +
            (v2.x + v2.y + v2.z + v2.w) + (v3.x + v3.y + v3.z + v3.w);
  }
  float m = fmaxf(fmaxf(sv[0], sv[1]), fmaxf(sv[2], sv[3]));
  for (int o = 32; o > 0; o >>= 1) m = fmaxf(m, __shfl_xor(m, o));
  if ((t & 63) == 0) red[t >> 6] = m;
  __syncthreads();
  float gm = fmaxf(fmaxf(red[0], red[1]), fmaxf(red[2], red[3]));
  float e[4], s = 0.f;
  #pragma unroll
  for (int i = 0; i < 4; ++i) { e[i] = expf(sv[i] - gm); s += e[i]; }
  for (int o = 32; o > 0; o >>= 1) s += __shfl_xor(s, o);
  if ((t & 63) == 0) red[4 + (t >> 6)] = s;
  __syncthreads();
  float inv = 1.0f / (red[4] + red[5] + red[6] + red[7]);
  #pragma unroll
  for (int i = 0; i < 4; ++i) alpha[(size_t)n * 1024 + i * 256 + t] = e[i] * inv;
}

// ---- ctx[n][h] = sum_l alpha[n][l] * enc[n][l][h], reading A_packed coalesced ----
// block (kt, n): thread group c = t>>5 handles chunk-col c, lanes ls = t&31 slice l.
__global__ void ctx_k(const unsigned short* __restrict__ Ap, const float* __restrict__ alpha,
                      float* __restrict__ ctx) {
  const int kt = blockIdx.x, n = blockIdx.y, t = threadIdx.x;
  __shared__ float al[1024];
  for (int i = t; i < 1024; i += 256) al[i] = alpha[n * 1024 + i];
  __syncthreads();
  const int c = t >> 5, ls = t & 31;
  float acc[8] = {0.f, 0.f, 0.f, 0.f, 0.f, 0.f, 0.f, 0.f};
  #pragma unroll 4
  for (int lb = 0; lb < 32; ++lb) {
    int l = lb * 32 + ls;
    int M = n * 1024 + l;
    int T = M >> 7, m = M & 127;
    us8 v = *(const us8*)(Ap + ((((size_t)T * 16 + kt) * 8 + c) * 128 + m) * 8);
    float w = al[l];
    #pragma unroll
    for (int j = 0; j < 8; ++j) acc[j] += w * b2f(v[j]);
  }
  #pragma unroll
  for (int off = 1; off <= 16; off <<= 1)
    #pragma unroll
    for (int j = 0; j < 8; ++j) acc[j] += __shfl_xor(acc[j], off);
  if (ls == 0) {
    #pragma unroll
    for (int j = 0; j < 8; ++j) ctx[(size_t)n * 1024 + kt * 64 + c * 8 + j] = acc[j];
  }
}

// ---- h_att[n][j] = ctx[n] . W_att[:,j] + b_att[j] -> d_out[0..65535] ----
__global__ void hatt_k(const float* __restrict__ ctx, const float* __restrict__ W_att,
                       const float* __restrict__ b_att, float* __restrict__ out) {
  __shared__ float cs[1024];
  int n = blockIdx.y;
  int j = blockIdx.x * 256 + threadIdx.x;
  for (int i = threadIdx.x; i < 1024; i += 256) cs[i] = ctx[(size_t)n * 1024 + i];
  __syncthreads();
  float s = 0.f;
  #pragma unroll 8
  for (int k = 0; k < 1024; ++k) s += cs[k] * W_att[(size_t)k * 1024 + j];
  out[n * 1024 + j] = s + b_att[j];
}

extern "C" void kernel_launch(void* const* d_in, const int* in_sizes, int n_in,
                              void* d_out, int out_size, void* d_ws, size_t ws_size,
                              hipStream_t stream) {
  const float* dec_h = (const float*)d_in[0];
  const float* enc   = (const float*)d_in[1];
  const float* W_dec = (const float*)d_in[2];
  const float* b_dec = (const float*)d_in[3];
  const float* W_enc = (const float*)d_in[4];
  const float* b_enc = (const float*)d_in[5];
  const float* W_one = (const float*)d_in[6];
  // d_in[7] = b_one: softmax shift-invariant -> unused
  const float* W_att = (const float*)d_in[8];
  const float* b_att = (const float*)d_in[9];
  float* out = (float*)d_out;

  char* ws = (char*)d_ws;
  const size_t OFF_A   = 0;                        // 134217728
  const size_t OFF_B   = 134217728;                // 2097152
  const size_t OFF_ADD = OFF_B + 2097152;          // 262144
  const size_t OFF_SP  = OFF_ADD + 262144;         // 4194304
  const size_t OFF_CTX = OFF_SP + 4194304;         // 262144
  const size_t NEED    = OFF_CTX + 262144;         // ~134.5 MiB
  if (ws_size < NEED) {
    fprintf(stderr, "kernel_launch: ws too small (%zu < %zu)\n", ws_size, NEED);
    return;
  }
  unsigned short* Ap = (unsigned short*)(ws + OFF_A);
  unsigned short* Bp = (unsigned short*)(ws + OFF_B);
  float* addterm = (float*)(ws + OFF_ADD);
  float* spart   = (float*)(ws + OFF_SP);
  float* ctx     = (float*)(ws + OFF_CTX);
  float* alpha   = out + 65536;

  pack_a<<<8192, 256, 0, stream>>>(enc, Ap);
  pack_b<<<128, 256, 0, stream>>>(W_enc, Bp);
  dterm_k<<<dim3(4, 64), 256, 0, stream>>>(dec_h, W_dec, b_dec, b_enc, addterm);
  score_gemm<<<4096, 256, 0, stream>>>(Ap, Bp, addterm, W_one, spart);
  softmax_k<<<64, 256, 0, stream>>>(spart, alpha);
  ctx_k<<<dim3(16, 64), 256, 0, stream>>>(Ap, alpha, ctx);
  hatt_k<<<dim3(4, 64), 256, 0, stream>>>(ctx, W_att, b_att, out);
}

// Round 5
// 688.981 us; speedup vs baseline: 1.2437x; 1.0361x over previous
//
#include <hip/hip_runtime.h>
#include <cstdio>
#include <cstdint>

// Bahdanau attention, N=64, L=1024, H=1024.
//   d = dec_h @ W_dec + b_dec
//   e = enc @ W_enc   (65536x1024x1024 bf16 MFMA GEMM, fused epilogue)
//   scores = tanh(d+e+b_enc) . W_one ; alpha = softmax(scores) (b_one drops)
//   ctx = alpha @ enc ; h_att = ctx @ W_att + b_att
//
// 4 launches: prep (pack_b + dterm + pack_a), score_gemm,
// ctx_fused (per-block redundant softmax + ctx slice; NO grid sync —
// cooperative launch does not work in this harness, R4), hatt.
//
// Packed layout (16B chunks): chunk index = ((T*16 + kt)*8 + c)*128 + m
//   T = row>>7, m = row&127, kt = col>>6, c = (col&63)>>3.

typedef __bf16 bf16x8 __attribute__((ext_vector_type(8)));
typedef float f32x4 __attribute__((ext_vector_type(4)));
typedef unsigned short us8 __attribute__((ext_vector_type(8)));

static __device__ __forceinline__ unsigned short f2b(float f) {
  union { float f; unsigned u; } v; v.f = f;
  unsigned r = (v.u + 0x7fffu + ((v.u >> 16) & 1u)) >> 16;  // RNE
  return (unsigned short)r;
}
static __device__ __forceinline__ float b2f(unsigned short u) {
  union { unsigned u; float f; } v; v.u = ((unsigned)u) << 16;
  return v.f;
}
static __device__ __forceinline__ void gl_lds16(const void* g, void* l) {
  __builtin_amdgcn_global_load_lds(
      (const __attribute__((address_space(1))) unsigned int*)g,
      (__attribute__((address_space(3))) unsigned int*)l, 16, 0, 0);
}
// branch-free tanh: (u-1)/(u+1), u = 2^(2*log2e*|x|); err ~1e-7
static __device__ __forceinline__ float fast_tanh(float x) {
  float ax = __builtin_fminf(__builtin_fabsf(x), 18.0f);
  float u = __builtin_amdgcn_exp2f(ax * 2.88539008177792681f);
  float t = (u - 1.0f) * __builtin_amdgcn_rcpf(u + 1.0f);
  return __builtin_copysignf(t, x);
}

// ---- prep: blocks [0,128) pack_b, [128,384) dterm, [384, 8576) pack_a ----
// XOR-swizzled LDS tile: chunk (row m, chunk c) -> slot m*8 + (c ^ (m&7)).
__global__ __launch_bounds__(256) void prep_k(
    const float* __restrict__ enc, unsigned short* __restrict__ Ap,
    const float* __restrict__ W_enc, unsigned short* __restrict__ Bp,
    const float* __restrict__ dec_h, const float* __restrict__ W_dec,
    const float* __restrict__ b_dec, const float* __restrict__ b_enc,
    float* __restrict__ addterm) {
  __shared__ __align__(16) unsigned short tile[8192];  // 16 KB
  const int bid = blockIdx.x;
  const int t = threadIdx.x;

  if (bid < 128) {
    // ---- pack_b: W_enc f32 [k][n] -> Bp bf16 tiled (transposed) ----
    const int Tn = bid >> 4, kt = bid & 15;
    #pragma unroll
    for (int it = 0; it < 8; ++it) {
      int idx = it * 256 + t;
      int kk = idx >> 5, n4 = idx & 31;  // 64 k-rows x 32 float4
      const float4 v = *(const float4*)(W_enc + (size_t)(kt * 64 + kk) * 1024 + Tn * 128 + n4 * 4);
      int c = kk >> 3, j = kk & 7;
      #pragma unroll
      for (int x = 0; x < 4; ++x) {
        int mm = n4 * 4 + x;
        float fv = (x == 0) ? v.x : (x == 1) ? v.y : (x == 2) ? v.z : v.w;
        tile[(mm * 8 + (c ^ (mm & 7))) * 8 + j] = f2b(fv);
      }
    }
    __syncthreads();
    #pragma unroll
    for (int it = 0; it < 4; ++it) {
      int p = it * 256 + t;
      int c = p >> 7, m = p & 127;
      us8 v = *(const us8*)&tile[(m * 8 + (c ^ (m & 7))) * 8];
      *(us8*)(Bp + ((size_t)bid * 1024 + p) * 8) = v;
    }
  } else if (bid < 384) {
    // ---- dterm: addterm[n][j] = dec_h[n] . W_dec[:,j] + b_dec[j] + b_enc[j] ----
    const int bid2 = bid - 128;
    const int jb = bid2 & 3, n = bid2 >> 2;
    float* xs = (float*)tile;
    for (int i = t; i < 1024; i += 256) xs[i] = dec_h[n * 1024 + i];
    __syncthreads();
    int j = jb * 256 + t;
    float s = 0.f;
    #pragma unroll 8
    for (int k = 0; k < 1024; ++k) s += xs[k] * W_dec[(size_t)k * 1024 + j];
    addterm[n * 1024 + j] = s + b_dec[j] + b_enc[j];
  } else {
    // ---- pack_a: enc f32 [65536][1024] -> Ap bf16 tiled ----
    const int ba = bid - 384;            // 8192 = T(512) x kt(16)
    const int T = ba >> 4, kt = ba & 15;
    #pragma unroll
    for (int it = 0; it < 8; ++it) {
      int idx = it * 256 + t;
      int m = idx >> 4, c4 = idx & 15;   // 128 rows x 16 float4
      const float4 v = *(const float4*)(enc + (size_t)(T * 128 + m) * 1024 + kt * 64 + c4 * 4);
      ushort4 o;
      o.x = f2b(v.x); o.y = f2b(v.y); o.z = f2b(v.z); o.w = f2b(v.w);
      int c = c4 >> 1, half = c4 & 1;
      *(ushort4*)&tile[(m * 8 + (c ^ (m & 7))) * 8 + half * 4] = o;
    }
    __syncthreads();
    #pragma unroll
    for (int it = 0; it < 4; ++it) {
      int p = it * 256 + t;              // out chunk pos = c*128 + m
      int c = p >> 7, m = p & 127;
      us8 v = *(const us8*)&tile[(m * 8 + (c ^ (m & 7))) * 8];
      *(us8*)(Ap + ((size_t)ba * 1024 + p) * 8) = v;
    }
  }
}

// ---- fused e-GEMM + tanh + dot(W_one): spart[row][16] partial scores ----
// 128x128 tile, BK=64, 4 waves 2x2, 4x4 of 16x16x32 MFMA each.
// Packed inputs -> every gl_lds16 reads 1KB contiguous global.
// XCD swizzle: 8 nb-siblings of one A-tile -> same flat%8 residue (same XCD).
__global__ __launch_bounds__(256) void score_gemm(
    const unsigned short* __restrict__ Ap, const unsigned short* __restrict__ Bp,
    const float* __restrict__ addterm, const float* __restrict__ Wone,
    float* __restrict__ spart) {
  __shared__ __align__(16) unsigned short lA[8192];  // 16 KB
  __shared__ __align__(16) unsigned short lB[8192];
  const int tid = threadIdx.x;
  const int lane = tid & 63, wave = tid >> 6;
  const int wm = wave >> 1, wn = wave & 1;
  const int q = lane >> 4, r = lane & 15;
  const int flat = blockIdx.x;
  const int nb = (flat >> 3) & 7;
  const int mb = ((flat >> 6) << 3) + (flat & 7);
  const size_t tileM = (size_t)mb * 128;
  const int tileN = nb * 128;

  f32x4 acc[4][4];
  #pragma unroll
  for (int i = 0; i < 4; ++i)
    #pragma unroll
    for (int j = 0; j < 4; ++j) acc[i][j] = (f32x4){0.f, 0.f, 0.f, 0.f};

  const unsigned short* gA[2][2];
  const unsigned short* gB[2][2];
  unsigned short* dA[2][2];
  unsigned short* dB[2][2];
  #pragma unroll
  for (int cc = 0; cc < 2; ++cc) {
    int c = wave * 2 + cc;
    #pragma unroll
    for (int i = 0; i < 2; ++i) {
      gA[cc][i] = Ap + ((((size_t)mb * 16) * 8 + c) * 128 + i * 64 + lane) * 8;
      gB[cc][i] = Bp + ((((size_t)nb * 16) * 8 + c) * 128 + i * 64 + lane) * 8;
      dA[cc][i] = &lA[(c * 128 + i * 64) * 8];
      dB[cc][i] = &lB[(c * 128 + i * 64) * 8];
    }
  }

  for (int kt = 0; kt < 16; ++kt) {
    __syncthreads();
    const size_t ko = (size_t)kt * 8192;
    gl_lds16(gA[0][0] + ko, dA[0][0]);
    gl_lds16(gA[0][1] + ko, dA[0][1]);
    gl_lds16(gA[1][0] + ko, dA[1][0]);
    gl_lds16(gA[1][1] + ko, dA[1][1]);
    gl_lds16(gB[0][0] + ko, dB[0][0]);
    gl_lds16(gB[0][1] + ko, dB[0][1]);
    gl_lds16(gB[1][0] + ko, dB[1][0]);
    gl_lds16(gB[1][1] + ko, dB[1][1]);
    __syncthreads();
    #pragma unroll
    for (int s = 0; s < 2; ++s) {
      bf16x8 af[4], bg[4];
      #pragma unroll
      for (int mi = 0; mi < 4; ++mi)
        af[mi] = *(const bf16x8*)&lA[((s * 4 + q) * 128 + wm * 64 + mi * 16 + r) * 8];
      #pragma unroll
      for (int ni = 0; ni < 4; ++ni)
        bg[ni] = *(const bf16x8*)&lB[((s * 4 + q) * 128 + wn * 64 + ni * 16 + r) * 8];
      #pragma unroll
      for (int mi = 0; mi < 4; ++mi)
        #pragma unroll
        for (int ni = 0; ni < 4; ++ni)
          acc[mi][ni] = __builtin_amdgcn_mfma_f32_16x16x32_bf16(af[mi], bg[ni], acc[mi][ni], 0, 0, 0);
    }
  }

  const int nrow = (int)(tileM >> 10);
  float addv[4], wv[4];
  #pragma unroll
  for (int ni = 0; ni < 4; ++ni) {
    int col = tileN + wn * 64 + ni * 16 + r;
    addv[ni] = addterm[nrow * 1024 + col];
    wv[ni] = Wone[col];
  }
  #pragma unroll
  for (int mi = 0; mi < 4; ++mi) {
    #pragma unroll
    for (int rr = 0; rr < 4; ++rr) {
      float s = 0.f;
      #pragma unroll
      for (int ni = 0; ni < 4; ++ni)
        s += fast_tanh(acc[mi][ni][rr] + addv[ni]) * wv[ni];
      s += __shfl_xor(s, 1);
      s += __shfl_xor(s, 2);
      s += __shfl_xor(s, 4);
      s += __shfl_xor(s, 8);
      if (r == 0) {
        size_t row = tileM + wm * 64 + mi * 16 + q * 4 + rr;
        spart[row * 16 + nb * 2 + wn] = s;
      }
    }
  }
}

// ---- ctx_fused: block (kt, n) recomputes softmax(n) from spart locally,
// then computes ctx[n][kt*64 .. kt*64+63]; kt==0 block writes alpha. ----
__global__ __launch_bounds__(256) void ctx_fused(
    const float* __restrict__ spart, float* __restrict__ alpha,
    const unsigned short* __restrict__ Ap, float* __restrict__ ctx) {
  const int kt = blockIdx.x, n = blockIdx.y, t = threadIdx.x;
  __shared__ float red[8];
  __shared__ float al[1024];

  // softmax over row n (redundant per kt; ~16KB spart row is L2-resident)
  float sv[4];
  #pragma unroll
  for (int i = 0; i < 4; ++i) {
    int l = i * 256 + t;
    const float4* p = (const float4*)(spart + ((size_t)n * 1024 + l) * 16);
    float4 v0 = p[0], v1 = p[1], v2 = p[2], v3 = p[3];
    sv[i] = (v0.x + v0.y + v0.z + v0.w) + (v1.x + v1.y + v1.z + v1.w) +
            (v2.x + v2.y + v2.z + v2.w) + (v3.x + v3.y + v3.z + v3.w);
  }
  float m = fmaxf(fmaxf(sv[0], sv[1]), fmaxf(sv[2], sv[3]));
  for (int o = 32; o > 0; o >>= 1) m = fmaxf(m, __shfl_xor(m, o));
  if ((t & 63) == 0) red[t >> 6] = m;
  __syncthreads();
  float gm = fmaxf(fmaxf(red[0], red[1]), fmaxf(red[2], red[3]));
  float e[4], s = 0.f;
  #pragma unroll
  for (int i = 0; i < 4; ++i) { e[i] = expf(sv[i] - gm); s += e[i]; }
  for (int o = 32; o > 0; o >>= 1) s += __shfl_xor(s, o);
  if ((t & 63) == 0) red[4 + (t >> 6)] = s;
  __syncthreads();
  float inv = 1.0f / (red[4] + red[5] + red[6] + red[7]);
  #pragma unroll
  for (int i = 0; i < 4; ++i) {
    float a = e[i] * inv;
    al[i * 256 + t] = a;
    if (kt == 0) alpha[(size_t)n * 1024 + i * 256 + t] = a;
  }
  __syncthreads();

  // ctx slice: thread group c = t>>5 handles chunk-col c, lanes ls = t&31 slice l
  const int c = t >> 5, ls = t & 31;
  float acc[8] = {0.f, 0.f, 0.f, 0.f, 0.f, 0.f, 0.f, 0.f};
  #pragma unroll 4
  for (int lb = 0; lb < 32; ++lb) {
    int l = lb * 32 + ls;
    int M = n * 1024 + l;
    int T = M >> 7, mm = M & 127;
    us8 v = *(const us8*)(Ap + ((((size_t)T * 16 + kt) * 8 + c) * 128 + mm) * 8);
    float w = al[l];
    #pragma unroll
    for (int j = 0; j < 8; ++j) acc[j] += w * b2f(v[j]);
  }
  #pragma unroll
  for (int off = 1; off <= 16; off <<= 1)
    #pragma unroll
    for (int j = 0; j < 8; ++j) acc[j] += __shfl_xor(acc[j], off);
  if (ls == 0) {
    #pragma unroll
    for (int j = 0; j < 8; ++j) ctx[(size_t)n * 1024 + kt * 64 + c * 8 + j] = acc[j];
  }
}

// ---- h_att[n][j] = ctx[n] . W_att[:,j] + b_att[j] -> d_out[0..65535] ----
__global__ void hatt_k(const float* __restrict__ ctx, const float* __restrict__ W_att,
                       const float* __restrict__ b_att, float* __restrict__ out) {
  __shared__ float cs[1024];
  int n = blockIdx.y;
  int j = blockIdx.x * 256 + threadIdx.x;
  for (int i = threadIdx.x; i < 1024; i += 256) cs[i] = ctx[(size_t)n * 1024 + i];
  __syncthreads();
  float s = 0.f;
  #pragma unroll 8
  for (int k = 0; k < 1024; ++k) s += cs[k] * W_att[(size_t)k * 1024 + j];
  out[n * 1024 + j] = s + b_att[j];
}

extern "C" void kernel_launch(void* const* d_in, const int* in_sizes, int n_in,
                              void* d_out, int out_size, void* d_ws, size_t ws_size,
                              hipStream_t stream) {
  const float* dec_h = (const float*)d_in[0];
  const float* enc   = (const float*)d_in[1];
  const float* W_dec = (const float*)d_in[2];
  const float* b_dec = (const float*)d_in[3];
  const float* W_enc = (const float*)d_in[4];
  const float* b_enc = (const float*)d_in[5];
  const float* W_one = (const float*)d_in[6];
  // d_in[7] = b_one: softmax shift-invariant -> unused
  const float* W_att = (const float*)d_in[8];
  const float* b_att = (const float*)d_in[9];
  float* out = (float*)d_out;

  char* ws = (char*)d_ws;
  const size_t OFF_A   = 0;                        // 134217728
  const size_t OFF_B   = 134217728;                // 2097152
  const size_t OFF_ADD = OFF_B + 2097152;          // 262144
  const size_t OFF_SP  = OFF_ADD + 262144;         // 4194304
  const size_t OFF_CTX = OFF_SP + 4194304;         // 262144
  const size_t NEED    = OFF_CTX + 262144;
  if (ws_size < NEED) {
    fprintf(stderr, "kernel_launch: ws too small (%zu < %zu)\n", ws_size, NEED);
    return;
  }
  unsigned short* Ap = (unsigned short*)(ws + OFF_A);
  unsigned short* Bp = (unsigned short*)(ws + OFF_B);
  float* addterm = (float*)(ws + OFF_ADD);
  float* spart   = (float*)(ws + OFF_SP);
  float* ctx     = (float*)(ws + OFF_CTX);
  float* alpha   = out + 65536;

  prep_k<<<8576, 256, 0, stream>>>(enc, Ap, W_enc, Bp, dec_h, W_dec, b_dec, b_enc, addterm);
  score_gemm<<<4096, 256, 0, stream>>>(Ap, Bp, addterm, W_one, spart);
  ctx_fused<<<dim3(16, 64), 256, 0, stream>>>(spart, alpha, Ap, ctx);
  hatt_k<<<dim3(4, 64), 256, 0, stream>>>(ctx, W_att, b_att, out);
}